// Round 1
// baseline (318.210 us; speedup 1.0000x reference)
//
#include <hip/hip_runtime.h>

// MegaNeRF fused MoE-MLP for MI355X (gfx950).
// Inputs (fp32): x(N,93), centroids(8,3), W1(8,90,256), b1(8,256),
//                W2(8,256,256), b2(8,256), W3(8,256,4), b3(8,4)
// Output (fp32): (N,4) = sum_e w[n,e] * MLP_e(x[n,3:])
//
// Strategy: bf16 MFMA (16x16x32) for all three GEMMs, fp32 accum.
// Weights pre-packed to B-fragment-native bf16 layout in d_ws (~1.5MB needed).

typedef __attribute__((ext_vector_type(8))) short   s16x8;
typedef __attribute__((ext_vector_type(4))) float   f32x4;

#define NPTS  65536
#define E_    8
#define DIN   90
#define H_    256
#define DOUT  4

// packed weight layout: [e][ct][ks][lane][j] bf16, 512 elems per (e,ct,ks)
#define W1P_ELEMS (E_*16*3*512)   // K padded to 96 -> 3 ksteps
#define W2P_ELEMS (E_*16*8*512)   // K=256 -> 8 ksteps
#define W3P_ELEMS (E_*1*8*512)    // N padded 4->16, K=256
#define W2P_OFF   (W1P_ELEMS)
#define W3P_OFF   (W1P_ELEMS + W2P_ELEMS)
#define WSP_TOTAL (W1P_ELEMS + W2P_ELEMS + W3P_ELEMS)

__device__ __forceinline__ unsigned short f2bf(float f) {
  union { float f; unsigned u; } v; v.f = f;
  unsigned u = v.u;
  u += 0x7fffu + ((u >> 16) & 1u);   // round-to-nearest-even
  return (unsigned short)(u >> 16);
}

// ---------------- prep: pack W1/W2/W3 fp32 -> bf16 fragment layout ----------
__global__ void prep_pack(const float* __restrict__ W1,
                          const float* __restrict__ W2,
                          const float* __restrict__ W3,
                          unsigned short* __restrict__ P) {
  int idx = blockIdx.x * blockDim.x + threadIdx.x;
  if (idx >= WSP_TOTAL) return;
  float val;
  if (idx < W2P_OFF) {                       // W1: (e,90,256), K padded 96
    int f = idx;
    int j = f & 7, l = (f >> 3) & 63, t = f >> 9;
    int ks = t % 3; t /= 3;
    int ct = t & 15, e = t >> 4;
    int k = ks*32 + (l>>4)*8 + j;
    int n = ct*16 + (l & 15);
    val = (k < DIN) ? W1[((size_t)e*DIN + k)*H_ + n] : 0.f;
  } else if (idx < W3P_OFF) {                // W2: (e,256,256)
    int f = idx - W2P_OFF;
    int j = f & 7, l = (f >> 3) & 63, t = f >> 9;
    int ks = t & 7; t >>= 3;
    int ct = t & 15, e = t >> 4;
    int k = ks*32 + (l>>4)*8 + j;
    int n = ct*16 + (l & 15);
    val = W2[((size_t)e*H_ + k)*H_ + n];
  } else {                                   // W3: (e,256,4), N padded to 16
    int f = idx - W3P_OFF;
    int j = f & 7, l = (f >> 3) & 63, t = f >> 9;
    int ks = t & 7, e = t >> 3;
    int k = ks*32 + (l>>4)*8 + j;
    int n = l & 15;
    val = (n < DOUT) ? W3[((size_t)e*H_ + k)*DOUT + n] : 0.f;
  }
  P[idx] = f2bf(val);
}

// ---------------- fused main kernel ----------------------------------------
__global__ __launch_bounds__(256)
void meganerf_fused(const float* __restrict__ x,
                    const float* __restrict__ cen,
                    const float* __restrict__ b1,
                    const float* __restrict__ b2,
                    const float* __restrict__ b3,
                    const unsigned short* __restrict__ P,
                    float* __restrict__ out) {
  // LDS: feats tile [64][128] bf16 (cols 0..95 used), h buffer [64][256] bf16,
  // routing weights [64][8] f32. XOR swizzle byte ^= (row&7)<<4 on both.
  __shared__ __attribute__((aligned(16))) unsigned short sF[64*128]; // 16KB
  __shared__ __attribute__((aligned(16))) unsigned short sH[64*256]; // 32KB
  __shared__ float sW[64*8];                                         // 2KB
  __shared__ int sActive;

  const int tid  = threadIdx.x;
  const int wid  = tid >> 6;
  const int lane = tid & 63;
  const int lg   = lane >> 4;   // k-group / row-group
  const int lr   = lane & 15;   // row (A) / col (B,D)
  const int row0 = blockIdx.x * 64;

  if (tid == 0) sActive = 0;
  __syncthreads();

  // ---- stage feats -> bf16 swizzled LDS (pad cols 90..95 with 0)
  for (int i = tid; i < 64*96; i += 256) {
    int r = i / 96, c = i - r*96;
    float v = (c < DIN) ? x[(size_t)(row0 + r)*93 + 3 + c] : 0.f;
    int byt = (c*2) ^ ((r & 7) << 4);
    sF[r*128 + (byt >> 1)] = f2bf(v);
  }
  // ---- routing weights (one thread per row)
  if (tid < 64) {
    const float* xr = x + (size_t)(row0 + tid)*93;
    float px = xr[0], py = xr[1], pz = xr[2];
    float d[E_], dmin = 1e30f;
    #pragma unroll
    for (int e = 0; e < E_; e++) {
      float dx = px - cen[e*3+0], dy = py - cen[e*3+1], dz = pz - cen[e*3+2];
      d[e] = sqrtf(dx*dx + dy*dy + dz*dz);
      dmin = fminf(dmin, d[e]);
    }
    float s = 0.f, inv[E_];
    #pragma unroll
    for (int e = 0; e < E_; e++) {
      float iv = (d[e] > 2.0f*dmin) ? 0.f : 1.0f/(d[e] + 1e-8f);
      inv[e] = iv; s += iv;
    }
    float rs = 1.0f/s; int m = 0;
    #pragma unroll
    for (int e = 0; e < E_; e++) {
      float w = inv[e]*rs;
      sW[tid*8 + e] = w;
      if (w > 0.f) m |= (1 << e);
    }
    atomicOr(&sActive, m);
  }
  __syncthreads();
  const int amask = sActive;

  float oacc[4] = {0.f, 0.f, 0.f, 0.f};

  for (int e = 0; e < E_; e++) {
    if (!((amask >> e) & 1)) continue;

    f32x4 acc[4][4];
    // ================= G1: h1 = relu(feats @ W1 + b1), K=96 ================
    #pragma unroll
    for (int mt = 0; mt < 4; mt++)
      #pragma unroll
      for (int nt = 0; nt < 4; nt++) acc[mt][nt] = (f32x4){0.f,0.f,0.f,0.f};
    #pragma unroll
    for (int ks = 0; ks < 3; ks++) {
      s16x8 a[4];
      #pragma unroll
      for (int mt = 0; mt < 4; mt++) {
        int row = mt*16 + lr;
        int byt = (ks*64 + lg*16) ^ ((row & 7) << 4);
        a[mt] = *(const s16x8*)&sF[row*128 + (byt >> 1)];
      }
      #pragma unroll
      for (int nt = 0; nt < 4; nt++) {
        int bi = (((e*16 + (wid*4 + nt))*3 + ks) << 9) + lane*8;
        s16x8 b = *(const s16x8*)&P[bi];
        #pragma unroll
        for (int mt = 0; mt < 4; mt++)
          acc[mt][nt] = __builtin_amdgcn_mfma_f32_16x16x32_bf16(a[mt], b, acc[mt][nt], 0, 0, 0);
      }
    }
    __syncthreads();   // previous expert's G3 reads of sH complete
    // bias + relu -> sH (h1)
    #pragma unroll
    for (int nt = 0; nt < 4; nt++) {
      int col = (wid*4 + nt)*16 + lr;
      float bv = b1[e*H_ + col];
      #pragma unroll
      for (int mt = 0; mt < 4; mt++) {
        #pragma unroll
        for (int r = 0; r < 4; r++) {
          int row = mt*16 + lg*4 + r;
          float v = fmaxf(acc[mt][nt][r] + bv, 0.f);
          int byt = (col*2) ^ ((row & 7) << 4);
          sH[row*256 + (byt >> 1)] = f2bf(v);
        }
      }
    }
    __syncthreads();
    // ================= G2: h2 = relu(h1 @ W2 + b2), K=256 ==================
    #pragma unroll
    for (int mt = 0; mt < 4; mt++)
      #pragma unroll
      for (int nt = 0; nt < 4; nt++) acc[mt][nt] = (f32x4){0.f,0.f,0.f,0.f};
    #pragma unroll
    for (int ks = 0; ks < 8; ks++) {
      s16x8 a[4];
      #pragma unroll
      for (int mt = 0; mt < 4; mt++) {
        int row = mt*16 + lr;
        int byt = (ks*64 + lg*16) ^ ((row & 7) << 4);
        a[mt] = *(const s16x8*)&sH[row*256 + (byt >> 1)];
      }
      #pragma unroll
      for (int nt = 0; nt < 4; nt++) {
        int bi = W2P_OFF + (((e*16 + (wid*4 + nt))*8 + ks) << 9) + lane*8;
        s16x8 b = *(const s16x8*)&P[bi];
        #pragma unroll
        for (int mt = 0; mt < 4; mt++)
          acc[mt][nt] = __builtin_amdgcn_mfma_f32_16x16x32_bf16(a[mt], b, acc[mt][nt], 0, 0, 0);
      }
    }
    __syncthreads();   // all reads of h1 done before overwrite
    // bias + relu -> sH (h2)
    #pragma unroll
    for (int nt = 0; nt < 4; nt++) {
      int col = (wid*4 + nt)*16 + lr;
      float bv = b2[e*H_ + col];
      #pragma unroll
      for (int mt = 0; mt < 4; mt++) {
        #pragma unroll
        for (int r = 0; r < 4; r++) {
          int row = mt*16 + lg*4 + r;
          float v = fmaxf(acc[mt][nt][r] + bv, 0.f);
          int byt = (col*2) ^ ((row & 7) << 4);
          sH[row*256 + (byt >> 1)] = f2bf(v);
        }
      }
    }
    __syncthreads();
    // ================= G3: out_e = h2 @ W3 + b3 (N padded to 16) ===========
    // wave w handles rows w*16 .. w*16+15
    f32x4 acc3 = (f32x4){0.f,0.f,0.f,0.f};
    #pragma unroll
    for (int ks = 0; ks < 8; ks++) {
      int row = wid*16 + lr;
      int byt = (ks*64 + lg*16) ^ ((row & 7) << 4);
      s16x8 a = *(const s16x8*)&sH[row*256 + (byt >> 1)];
      s16x8 b = *(const s16x8*)&P[W3P_OFF + ((e*8 + ks) << 9) + lane*8];
      acc3 = __builtin_amdgcn_mfma_f32_16x16x32_bf16(a, b, acc3, 0, 0, 0);
    }
    if (lr < DOUT) {
      float bv = b3[e*DOUT + lr];
      #pragma unroll
      for (int r = 0; r < 4; r++) {
        int row = wid*16 + lg*4 + r;
        float wv = sW[row*8 + e];
        oacc[r] += wv * (acc3[r] + bv);
      }
    }
  }

  // ---- final store: (row, col) owned by exactly one lane
  if (lr < DOUT) {
    #pragma unroll
    for (int r = 0; r < 4; r++) {
      int row = wid*16 + lg*4 + r;
      out[(size_t)(row0 + row)*DOUT + lr] = oacc[r];
    }
  }
}

// ---------------- launcher --------------------------------------------------
extern "C" void kernel_launch(void* const* d_in, const int* in_sizes, int n_in,
                              void* d_out, int out_size, void* d_ws, size_t ws_size,
                              hipStream_t stream) {
  const float* x   = (const float*)d_in[0];
  const float* cen = (const float*)d_in[1];
  const float* W1  = (const float*)d_in[2];
  const float* b1  = (const float*)d_in[3];
  const float* W2  = (const float*)d_in[4];
  const float* b2  = (const float*)d_in[5];
  const float* W3  = (const float*)d_in[6];
  const float* b3  = (const float*)d_in[7];
  unsigned short* P = (unsigned short*)d_ws;   // needs WSP_TOTAL*2 ≈ 1.5MB
  float* out = (float*)d_out;

  prep_pack<<<dim3((WSP_TOTAL + 255)/256), dim3(256), 0, stream>>>(W1, W2, W3, P);
  meganerf_fused<<<dim3(NPTS/64), dim3(256), 0, stream>>>(x, cen, b1, b2, b3, P, out);
}

// Round 2
// 178.538 us; speedup vs baseline: 1.7823x; 1.7823x over previous
//
#include <hip/hip_runtime.h>

// MegaNeRF fused MoE-MLP for MI355X (gfx950) — round 2: expert compaction.
// Inputs (fp32): x(N,93), centroids(8,3), W1(8,90,256), b1(8,256),
//                W2(8,256,256), b2(8,256), W3(8,256,4), b3(8,4)
// Output (fp32): (N,4) = sum_e w[n,e] * MLP_e(x[n,3:])
//
// Pipeline:
//   prep_pack:      weights fp32 -> bf16 MFMA B-fragment layout (ws)
//   route_compact:  per-expert compacted u16 point lists (ws)
//   expert_mlp:     per (expert, 64-pt tile): gather, 3x bf16-MFMA GEMM,
//                   atomicAdd weighted contribution into zeroed d_out.

typedef __attribute__((ext_vector_type(8))) short   s16x8;
typedef __attribute__((ext_vector_type(4))) float   f32x4;

#define NPTS  65536
#define E_    8
#define DIN   90
#define H_    256
#define DOUT  4

// packed weight layout: [e][ct][ks][lane][j] bf16, 512 elems per (e,ct,ks)
#define W1P_ELEMS (E_*16*3*512)   // K padded to 96 -> 3 ksteps
#define W2P_ELEMS (E_*16*8*512)   // K=256 -> 8 ksteps
#define W3P_ELEMS (E_*1*8*512)    // N padded 4->16, K=256
#define W2P_OFF   (W1P_ELEMS)
#define W3P_OFF   (W1P_ELEMS + W2P_ELEMS)
#define WSP_TOTAL (W1P_ELEMS + W2P_ELEMS + W3P_ELEMS)
#define WSP_BYTES (WSP_TOTAL*2)          // 1,507,328 B
#define CNT_OFF   WSP_BYTES              // int[8]
#define LIST_OFF  (WSP_BYTES + 32)       // u16[E_*NPTS] = 1 MB

__device__ __forceinline__ unsigned short f2bf(float f) {
  union { float f; unsigned u; } v; v.f = f;
  unsigned u = v.u;
  u += 0x7fffu + ((u >> 16) & 1u);   // round-to-nearest-even
  return (unsigned short)(u >> 16);
}

// ---------------- prep: pack W1/W2/W3 fp32 -> bf16 fragment layout ----------
__global__ void prep_pack(const float* __restrict__ W1,
                          const float* __restrict__ W2,
                          const float* __restrict__ W3,
                          unsigned short* __restrict__ P) {
  int idx = blockIdx.x * blockDim.x + threadIdx.x;
  if (idx >= WSP_TOTAL) return;
  float val;
  if (idx < W2P_OFF) {                       // W1: (e,90,256), K padded 96
    int f = idx;
    int j = f & 7, l = (f >> 3) & 63, t = f >> 9;
    int ks = t % 3; t /= 3;
    int ct = t & 15, e = t >> 4;
    int k = ks*32 + (l>>4)*8 + j;
    int n = ct*16 + (l & 15);
    val = (k < DIN) ? W1[((size_t)e*DIN + k)*H_ + n] : 0.f;
  } else if (idx < W3P_OFF) {                // W2: (e,256,256)
    int f = idx - W2P_OFF;
    int j = f & 7, l = (f >> 3) & 63, t = f >> 9;
    int ks = t & 7; t >>= 3;
    int ct = t & 15, e = t >> 4;
    int k = ks*32 + (l>>4)*8 + j;
    int n = ct*16 + (l & 15);
    val = W2[((size_t)e*H_ + k)*H_ + n];
  } else {                                   // W3: (e,256,4), N padded to 16
    int f = idx - W3P_OFF;
    int j = f & 7, l = (f >> 3) & 63, t = f >> 9;
    int ks = t & 7, e = t >> 3;
    int k = ks*32 + (l>>4)*8 + j;
    int n = l & 15;
    val = (n < DOUT) ? W3[((size_t)e*H_ + k)*DOUT + n] : 0.f;
  }
  P[idx] = f2bf(val);
}

// ---------------- routing + compaction into per-expert lists ----------------
__global__ __launch_bounds__(256)
void route_compact(const float* __restrict__ x,
                   const float* __restrict__ cen,
                   int* __restrict__ counts,
                   unsigned short* __restrict__ lists) {
  const int tid = threadIdx.x;
  const int gid = blockIdx.x * 256 + tid;
  __shared__ int lcnt[E_], lbase[E_];
  if (tid < E_) lcnt[tid] = 0;
  __syncthreads();

  const float* xr = x + (size_t)gid*93;
  float px = xr[0], py = xr[1], pz = xr[2];
  float d[E_], dmin = 1e30f;
  #pragma unroll
  for (int e = 0; e < E_; e++) {
    float dx = px - cen[e*3+0], dy = py - cen[e*3+1], dz = pz - cen[e*3+2];
    d[e] = sqrtf(dx*dx + dy*dy + dz*dz);
    dmin = fminf(dmin, d[e]);
  }
  int myoff[E_];
  int act = 0;
  #pragma unroll
  for (int e = 0; e < E_; e++) {
    bool a = !(d[e] > 2.0f*dmin);            // matches reference predicate
    if (a) { myoff[e] = atomicAdd(&lcnt[e], 1); act |= (1 << e); }
  }
  __syncthreads();
  if (tid < E_) lbase[tid] = atomicAdd(&counts[tid], lcnt[tid]);
  __syncthreads();
  #pragma unroll
  for (int e = 0; e < E_; e++)
    if ((act >> e) & 1)
      lists[e*NPTS + lbase[e] + myoff[e]] = (unsigned short)gid;
}

// ---------------- per-expert fused MLP over compacted tiles -----------------
__global__ __launch_bounds__(256)
void expert_mlp(const float* __restrict__ x,
                const float* __restrict__ cen,
                const float* __restrict__ b1,
                const float* __restrict__ b2,
                const float* __restrict__ b3,
                const unsigned short* __restrict__ P,
                const int* __restrict__ counts,
                const unsigned short* __restrict__ lists,
                float* __restrict__ out) {
  const int e   = blockIdx.y;
  const int cnt = counts[e];
  const int t   = blockIdx.x;
  if (t*64 >= cnt) return;

  __shared__ __attribute__((aligned(16))) unsigned short sF[64*128]; // 16KB
  __shared__ __attribute__((aligned(16))) unsigned short sH[64*256]; // 32KB
  __shared__ float          sWv[64];
  __shared__ unsigned short sIdx[64];

  const int tid  = threadIdx.x;
  const int wid  = tid >> 6;
  const int lane = tid & 63;
  const int lg   = lane >> 4;   // k-group / row-group
  const int lr   = lane & 15;   // row (A) / col (B,D)

  // ---- phase 1: load slot -> point index, recompute routing weight for e
  if (tid < 64) {
    int slot = t*64 + tid;
    int p = (slot < cnt) ? (int)lists[e*NPTS + slot] : 0;
    sIdx[tid] = (unsigned short)p;
    const float* xr = x + (size_t)p*93;
    float px = xr[0], py = xr[1], pz = xr[2];
    float d[E_], dmin = 1e30f;
    #pragma unroll
    for (int k = 0; k < E_; k++) {
      float dx = px - cen[k*3+0], dy = py - cen[k*3+1], dz = pz - cen[k*3+2];
      d[k] = sqrtf(dx*dx + dy*dy + dz*dz);
      dmin = fminf(dmin, d[k]);
    }
    float s = 0.f, inv[E_];
    #pragma unroll
    for (int k = 0; k < E_; k++) {
      float iv = (d[k] > 2.0f*dmin) ? 0.f : 1.0f/(d[k] + 1e-8f);
      inv[k] = iv; s += iv;
    }
    sWv[tid] = (slot < cnt) ? inv[e]/s : 0.f;
  }
  __syncthreads();

  // ---- stage feats -> bf16 swizzled LDS (cols 90..95 zero-padded)
  for (int i = tid; i < 64*96; i += 256) {
    int r = i / 96, c = i - r*96;
    int p = sIdx[r];
    float v = (c < DIN) ? x[(size_t)p*93 + 3 + c] : 0.f;
    int byt = (c*2) ^ ((r & 7) << 4);
    sF[r*128 + (byt >> 1)] = f2bf(v);
  }
  __syncthreads();

  f32x4 acc[4][4];
  // ================= G1: h1 = relu(feats @ W1 + b1), K=96 ==================
  #pragma unroll
  for (int mt = 0; mt < 4; mt++)
    #pragma unroll
    for (int nt = 0; nt < 4; nt++) acc[mt][nt] = (f32x4){0.f,0.f,0.f,0.f};
  #pragma unroll
  for (int ks = 0; ks < 3; ks++) {
    s16x8 a[4];
    #pragma unroll
    for (int mt = 0; mt < 4; mt++) {
      int row = mt*16 + lr;
      int byt = (ks*64 + lg*16) ^ ((row & 7) << 4);
      a[mt] = *(const s16x8*)&sF[row*128 + (byt >> 1)];
    }
    #pragma unroll
    for (int nt = 0; nt < 4; nt++) {
      int bi = (((e*16 + (wid*4 + nt))*3 + ks) << 9) + lane*8;
      s16x8 b = *(const s16x8*)&P[bi];
      #pragma unroll
      for (int mt = 0; mt < 4; mt++)
        acc[mt][nt] = __builtin_amdgcn_mfma_f32_16x16x32_bf16(a[mt], b, acc[mt][nt], 0, 0, 0);
    }
  }
  // bias + relu -> sH (h1)   (sH has no prior readers; no barrier needed)
  #pragma unroll
  for (int nt = 0; nt < 4; nt++) {
    int col = (wid*4 + nt)*16 + lr;
    float bv = b1[e*H_ + col];
    #pragma unroll
    for (int mt = 0; mt < 4; mt++) {
      #pragma unroll
      for (int r = 0; r < 4; r++) {
        int row = mt*16 + lg*4 + r;
        float v = fmaxf(acc[mt][nt][r] + bv, 0.f);
        int byt = (col*2) ^ ((row & 7) << 4);
        sH[row*256 + (byt >> 1)] = f2bf(v);
      }
    }
  }
  __syncthreads();
  // ================= G2: h2 = relu(h1 @ W2 + b2), K=256 ====================
  #pragma unroll
  for (int mt = 0; mt < 4; mt++)
    #pragma unroll
    for (int nt = 0; nt < 4; nt++) acc[mt][nt] = (f32x4){0.f,0.f,0.f,0.f};
  #pragma unroll
  for (int ks = 0; ks < 8; ks++) {
    s16x8 a[4];
    #pragma unroll
    for (int mt = 0; mt < 4; mt++) {
      int row = mt*16 + lr;
      int byt = (ks*64 + lg*16) ^ ((row & 7) << 4);
      a[mt] = *(const s16x8*)&sH[row*256 + (byt >> 1)];
    }
    #pragma unroll
    for (int nt = 0; nt < 4; nt++) {
      int bi = W2P_OFF + (((e*16 + (wid*4 + nt))*8 + ks) << 9) + lane*8;
      s16x8 b = *(const s16x8*)&P[bi];
      #pragma unroll
      for (int mt = 0; mt < 4; mt++)
        acc[mt][nt] = __builtin_amdgcn_mfma_f32_16x16x32_bf16(a[mt], b, acc[mt][nt], 0, 0, 0);
    }
  }
  __syncthreads();   // all reads of h1 done before overwrite
  // bias + relu -> sH (h2)
  #pragma unroll
  for (int nt = 0; nt < 4; nt++) {
    int col = (wid*4 + nt)*16 + lr;
    float bv = b2[e*H_ + col];
    #pragma unroll
    for (int mt = 0; mt < 4; mt++) {
      #pragma unroll
      for (int r = 0; r < 4; r++) {
        int row = mt*16 + lg*4 + r;
        float v = fmaxf(acc[mt][nt][r] + bv, 0.f);
        int byt = (col*2) ^ ((row & 7) << 4);
        sH[row*256 + (byt >> 1)] = f2bf(v);
      }
    }
  }
  __syncthreads();
  // ================= G3: out_e = h2 @ W3 + b3 (N padded to 16) =============
  f32x4 acc3 = (f32x4){0.f,0.f,0.f,0.f};
  #pragma unroll
  for (int ks = 0; ks < 8; ks++) {
    int row = wid*16 + lr;
    int byt = (ks*64 + lg*16) ^ ((row & 7) << 4);
    s16x8 a = *(const s16x8*)&sH[row*256 + (byt >> 1)];
    s16x8 b = *(const s16x8*)&P[W3P_OFF + ((e*8 + ks) << 9) + lane*8];
    acc3 = __builtin_amdgcn_mfma_f32_16x16x32_bf16(a, b, acc3, 0, 0, 0);
  }
  if (lr < DOUT) {
    float bv = b3[e*DOUT + lr];
    #pragma unroll
    for (int r = 0; r < 4; r++) {
      int row = wid*16 + lg*4 + r;
      float wv = sWv[row];
      if (wv != 0.f)
        atomicAdd(&out[(size_t)sIdx[row]*DOUT + lr], wv*(acc3[r] + bv));
    }
  }
}

// ---------------- launcher --------------------------------------------------
extern "C" void kernel_launch(void* const* d_in, const int* in_sizes, int n_in,
                              void* d_out, int out_size, void* d_ws, size_t ws_size,
                              hipStream_t stream) {
  const float* x   = (const float*)d_in[0];
  const float* cen = (const float*)d_in[1];
  const float* W1  = (const float*)d_in[2];
  const float* b1  = (const float*)d_in[3];
  const float* W2  = (const float*)d_in[4];
  const float* b2  = (const float*)d_in[5];
  const float* W3  = (const float*)d_in[6];
  const float* b3  = (const float*)d_in[7];

  unsigned short* P     = (unsigned short*)d_ws;
  int*            cnts  = (int*)((char*)d_ws + CNT_OFF);
  unsigned short* lists = (unsigned short*)((char*)d_ws + LIST_OFF);
  float* out = (float*)d_out;

  hipMemsetAsync(cnts, 0, 32, stream);
  hipMemsetAsync(out, 0, (size_t)NPTS*DOUT*sizeof(float), stream);
  prep_pack<<<dim3((WSP_TOTAL + 255)/256), dim3(256), 0, stream>>>(W1, W2, W3, P);
  route_compact<<<dim3(NPTS/256), dim3(256), 0, stream>>>(x, cen, cnts, lists);
  expert_mlp<<<dim3(NPTS/64, E_), dim3(256), 0, stream>>>(x, cen, b1, b2, b3, P,
                                                          cnts, lists, out);
}